// Round 1
// baseline (504.580 us; speedup 1.0000x reference)
//
#include <hip/hip_runtime.h>
#include <hip/hip_bf16.h>

#define S_LEN 2048
#define D_MODEL 1024
#define NH 16
#define HDIM 64
#define B_SZ 4

typedef __attribute__((ext_vector_type(8))) short bf16x8;
typedef __attribute__((ext_vector_type(4))) float f32x4;

__device__ inline void gld16(const __hip_bfloat16* g, __hip_bfloat16* l) {
    __builtin_amdgcn_global_load_lds(
        (const __attribute__((address_space(1))) unsigned int*)g,
        (__attribute__((address_space(3))) unsigned int*)l, 16, 0, 0);
}

// ---------------- fp32 -> bf16 convert (vectorized x4) ----------------
__global__ __launch_bounds__(256) void f2bf4_kernel(const float4* __restrict__ in,
                                                    __hip_bfloat162* __restrict__ out,
                                                    int n4) {
    int i = blockIdx.x * 256 + threadIdx.x;
    if (i < n4) {
        float4 v = in[i];
        __hip_bfloat162 a, b;
        a.x = __float2bfloat16(v.x); a.y = __float2bfloat16(v.y);
        b.x = __float2bfloat16(v.z); b.y = __float2bfloat16(v.w);
        out[2 * i]     = a;
        out[2 * i + 1] = b;
    }
}

// ---------------- shared GEMM mainloop: C[128x128] = X[128xK] * W[128xK]^T ----
// m97 structure: 4 waves, each wave a 64x64 quadrant = 4x4 of 16x16x32 MFMA.
__device__ inline void gemm_mainloop(const __hip_bfloat16* __restrict__ X,
                                     const __hip_bfloat16* __restrict__ W,
                                     __hip_bfloat16* As, __hip_bfloat16* Bs,
                                     int m0, int n0, f32x4 acc[4][4]) {
    const int tid = threadIdx.x;
    const int wv = tid >> 6, lane = tid & 63, l15 = lane & 15, quad = lane >> 4;
    const int rw = (wv >> 1) * 64, cw = (wv & 1) * 64;
    for (int k0 = 0; k0 < D_MODEL; k0 += 32) {
        __syncthreads();
#pragma unroll
        for (int i = 0; i < 2; i++) {
            int l = tid + 256 * i;
            int row = l >> 2, c8 = (l & 3) * 8;
            gld16(&X[(size_t)(m0 + row) * D_MODEL + k0 + c8], &As[row * 32 + c8]);
            gld16(&W[(size_t)(n0 + row) * D_MODEL + k0 + c8], &Bs[row * 32 + c8]);
        }
        __syncthreads();
        bf16x8 af[4], bfr[4];
#pragma unroll
        for (int t = 0; t < 4; t++)
            af[t] = *(const bf16x8*)&As[(rw + t * 16 + l15) * 32 + quad * 8];
#pragma unroll
        for (int t = 0; t < 4; t++)
            bfr[t] = *(const bf16x8*)&Bs[(cw + t * 16 + l15) * 32 + quad * 8];
#pragma unroll
        for (int mt = 0; mt < 4; mt++)
#pragma unroll
            for (int nt = 0; nt < 4; nt++)
                acc[mt][nt] = __builtin_amdgcn_mfma_f32_16x16x32_bf16(
                    af[mt], bfr[nt], acc[mt][nt], 0, 0, 0);
    }
}

// ---------------- QKV projection + RoPE + scatter to [B,H,S,hd] bf16 ---------
__global__ __launch_bounds__(256) void qkv_kernel(
    const __hip_bfloat16* __restrict__ X,
    const __hip_bfloat16* __restrict__ W0, const __hip_bfloat16* __restrict__ W1,
    const __hip_bfloat16* __restrict__ W2,
    const float* __restrict__ b0, const float* __restrict__ b1,
    const float* __restrict__ b2,
    const float* __restrict__ rc, const float* __restrict__ rs,
    __hip_bfloat16* __restrict__ Qo, __hip_bfloat16* __restrict__ Ko,
    __hip_bfloat16* __restrict__ Vo) {
    __shared__ __hip_bfloat16 As[128 * 32];
    __shared__ __hip_bfloat16 Bs[128 * 32];
    const int z = blockIdx.z;
    const __hip_bfloat16* W = (z == 0) ? W0 : ((z == 1) ? W1 : W2);
    const float* bias = (z == 0) ? b0 : ((z == 1) ? b1 : b2);
    f32x4 acc[4][4];
#pragma unroll
    for (int i = 0; i < 4; i++)
#pragma unroll
        for (int j = 0; j < 4; j++) acc[i][j] = (f32x4){0.f, 0.f, 0.f, 0.f};
    const int m0 = blockIdx.x * 128, n0 = blockIdx.y * 128;
    gemm_mainloop(X, W, As, Bs, m0, n0, acc);

    const int tid = threadIdx.x;
    const int wv = tid >> 6, lane = tid & 63, l15 = lane & 15, quad = lane >> 4;
    const int rw = (wv >> 1) * 64, cw = (wv & 1) * 64;

    if (z == 2) {
#pragma unroll
        for (int mt = 0; mt < 4; mt++)
#pragma unroll
            for (int r = 0; r < 4; r++) {
                int m = m0 + rw + mt * 16 + quad * 4 + r;
                int s = m & (S_LEN - 1), b = m >> 11;
#pragma unroll
                for (int nt = 0; nt < 4; nt++) {
                    int n = n0 + cw + nt * 16 + l15;
                    int h = n >> 6, hd = n & 63;
                    float v = acc[mt][nt][r] + bias[n];
                    Vo[(((size_t)(b * NH + h)) * S_LEN + s) * HDIM + hd] =
                        __float2bfloat16(v);
                }
            }
    } else {
        __hip_bfloat16* dst = (z == 0) ? Qo : Ko;
#pragma unroll
        for (int mt = 0; mt < 4; mt++)
#pragma unroll
            for (int r = 0; r < 4; r++) {
                int m = m0 + rw + mt * 16 + quad * 4 + r;
                int s = m & (S_LEN - 1), b = m >> 11;
#pragma unroll
                for (int nt = 0; nt < 2; nt++) {
                    int n1 = n0 + cw + nt * 16 + l15;
                    int h = n1 >> 6, hd1 = n1 & 63;  // hd1 in [0,32)
                    float y1 = acc[mt][nt][r] + bias[n1];
                    float y2 = acc[mt][nt + 2][r] + bias[n1 + 32];
                    float c1 = rc[s * HDIM + hd1], s1 = rs[s * HDIM + hd1];
                    float c2 = rc[s * HDIM + hd1 + 32], s2 = rs[s * HDIM + hd1 + 32];
                    size_t base = (((size_t)(b * NH + h)) * S_LEN + s) * HDIM;
                    dst[base + hd1]      = __float2bfloat16(y1 * c1 - y2 * s1);
                    dst[base + hd1 + 32] = __float2bfloat16(y2 * c2 + y1 * s2);
                }
            }
    }
}

// ---------------- flash attention: 64-q block, 4 waves x 16 q-rows ----------
#define KP 72  // LDS pitch (elements): rows 144B = 9*16B -> b128-aligned, 2-way banks
__global__ __launch_bounds__(256) void attn_kernel(
    const __hip_bfloat16* __restrict__ Q, const __hip_bfloat16* __restrict__ K,
    const __hip_bfloat16* __restrict__ V, __hip_bfloat16* __restrict__ CTX) {
    __shared__ __hip_bfloat16 Kl[64 * KP];
    __shared__ __hip_bfloat16 Vt[64 * KP];      // transposed: [dim][key]
    __shared__ __hip_bfloat16 Pl[4][16 * KP];   // per-wave P tile [q][key]
    const int tid = threadIdx.x;
    const int wv = tid >> 6, lane = tid & 63, l15 = lane & 15, quad = lane >> 4;
    const int bh = blockIdx.y;
    const int q0 = blockIdx.x * 64;
    const size_t off = (size_t)bh * S_LEN * HDIM;
    const __hip_bfloat16* Qp = Q + off;
    const __hip_bfloat16* Kp = K + off;
    const __hip_bfloat16* Vp = V + off;

    const int qrow = q0 + wv * 16 + l15;
    bf16x8 qf0 = *(const bf16x8*)&Qp[(size_t)qrow * HDIM + quad * 8];
    bf16x8 qf1 = *(const bf16x8*)&Qp[(size_t)qrow * HDIM + 32 + quad * 8];

    float m_i[4], l_i[4];
    f32x4 aco[4];
#pragma unroll
    for (int r = 0; r < 4; r++) { m_i[r] = -1e30f; l_i[r] = 0.f; }
#pragma unroll
    for (int nt = 0; nt < 4; nt++) aco[nt] = (f32x4){0.f, 0.f, 0.f, 0.f};

    const float SCL = 0.125f * 1.44269504088896340736f;  // 1/sqrt(64) * log2(e)
    const int diag = q0 >> 6;

    for (int kb = 0; kb <= diag; kb++) {
        const int k0 = kb * 64;
        __syncthreads();
        // stage K tile [key][dim], pitch KP
#pragma unroll
        for (int i = 0; i < 2; i++) {
            int l = tid + 256 * i;
            int ky = l >> 3, d0 = (l & 7) * 8;
            *(float4*)&Kl[ky * KP + d0] =
                *(const float4*)&Kp[(size_t)(k0 + ky) * HDIM + d0];
        }
        // stage V transposed: wave wv covers keys k0+wv*16 .. +15; lane = dim
        {
            unsigned short vv[16];
#pragma unroll
            for (int j = 0; j < 16; j++)
                vv[j] = *(const unsigned short*)&Vp[(size_t)(k0 + wv * 16 + j) * HDIM + lane];
            union { bf16x8 v; unsigned short u[8]; } pk;
#pragma unroll
            for (int j = 0; j < 8; j++) pk.u[j] = vv[j];
            *(bf16x8*)&Vt[lane * KP + wv * 16] = pk.v;
#pragma unroll
            for (int j = 0; j < 8; j++) pk.u[j] = vv[8 + j];
            *(bf16x8*)&Vt[lane * KP + wv * 16 + 8] = pk.v;
        }
        __syncthreads();

        // scores: 4 subtiles of 16 keys
        float sst[4][4];
        const bool dg = (kb == diag);
#pragma unroll
        for (int st = 0; st < 4; st++) {
            bf16x8 kf0 = *(const bf16x8*)&Kl[(st * 16 + l15) * KP + quad * 8];
            bf16x8 kf1 = *(const bf16x8*)&Kl[(st * 16 + l15) * KP + 32 + quad * 8];
            f32x4 sa = (f32x4){0.f, 0.f, 0.f, 0.f};
            sa = __builtin_amdgcn_mfma_f32_16x16x32_bf16(qf0, kf0, sa, 0, 0, 0);
            sa = __builtin_amdgcn_mfma_f32_16x16x32_bf16(qf1, kf1, sa, 0, 0, 0);
#pragma unroll
            for (int r = 0; r < 4; r++) {
                float sv = sa[r] * SCL;
                if (dg && (k0 + st * 16 + l15 > q0 + wv * 16 + quad * 4 + r))
                    sv = -1e30f;
                sst[st][r] = sv;
            }
        }
        // row max across the 16 lanes of each quad-group
        float mloc[4];
#pragma unroll
        for (int r = 0; r < 4; r++)
            mloc[r] = fmaxf(fmaxf(sst[0][r], sst[1][r]), fmaxf(sst[2][r], sst[3][r]));
#pragma unroll
        for (int o = 1; o < 16; o <<= 1)
#pragma unroll
            for (int r = 0; r < 4; r++)
                mloc[r] = fmaxf(mloc[r], __shfl_xor(mloc[r], o, 16));

        float al[4];
#pragma unroll
        for (int r = 0; r < 4; r++) {
            float mn = fmaxf(m_i[r], mloc[r]);
            al[r] = __builtin_exp2f(m_i[r] - mn);
            m_i[r] = mn;
        }
        float lsum[4] = {0.f, 0.f, 0.f, 0.f};
#pragma unroll
        for (int st = 0; st < 4; st++)
#pragma unroll
            for (int r = 0; r < 4; r++) {
                float p = __builtin_exp2f(sst[st][r] - m_i[r]);
                lsum[r] += p;
                Pl[wv][(quad * 4 + r) * KP + st * 16 + l15] = __float2bfloat16(p);
            }
#pragma unroll
        for (int o = 1; o < 16; o <<= 1)
#pragma unroll
            for (int r = 0; r < 4; r++) lsum[r] += __shfl_xor(lsum[r], o, 16);
#pragma unroll
        for (int r = 0; r < 4; r++) l_i[r] = l_i[r] * al[r] + lsum[r];
#pragma unroll
        for (int nt = 0; nt < 4; nt++)
#pragma unroll
            for (int r = 0; r < 4; r++) aco[nt][r] *= al[r];

        // PV: P (A-layout via LDS) x V (B-layout from transposed tile)
#pragma unroll
        for (int c = 0; c < 2; c++) {
            bf16x8 pf = *(const bf16x8*)&Pl[wv][l15 * KP + c * 32 + quad * 8];
#pragma unroll
            for (int nt = 0; nt < 4; nt++) {
                bf16x8 vf = *(const bf16x8*)&Vt[(nt * 16 + l15) * KP + c * 32 + quad * 8];
                aco[nt] = __builtin_amdgcn_mfma_f32_16x16x32_bf16(pf, vf, aco[nt], 0, 0, 0);
            }
        }
    }

    const int b = bh >> 4, h = bh & 15;
#pragma unroll
    for (int r = 0; r < 4; r++) {
        float inv = 1.0f / l_i[r];
        int qg = q0 + wv * 16 + quad * 4 + r;
#pragma unroll
        for (int nt = 0; nt < 4; nt++)
            CTX[((size_t)(b * S_LEN + qg)) * D_MODEL + h * HDIM + nt * 16 + l15] =
                __float2bfloat16(aco[nt][r] * inv);
    }
}

// ---------------- output projection: fp32 out = ctx @ Wo^T + bo --------------
__global__ __launch_bounds__(256) void outproj_kernel(
    const __hip_bfloat16* __restrict__ X, const __hip_bfloat16* __restrict__ W,
    const float* __restrict__ bias, float* __restrict__ OUT) {
    __shared__ __hip_bfloat16 As[128 * 32];
    __shared__ __hip_bfloat16 Bs[128 * 32];
    f32x4 acc[4][4];
#pragma unroll
    for (int i = 0; i < 4; i++)
#pragma unroll
        for (int j = 0; j < 4; j++) acc[i][j] = (f32x4){0.f, 0.f, 0.f, 0.f};
    const int m0 = blockIdx.x * 128, n0 = blockIdx.y * 128;
    gemm_mainloop(X, W, As, Bs, m0, n0, acc);
    const int tid = threadIdx.x;
    const int wv = tid >> 6, lane = tid & 63, l15 = lane & 15, quad = lane >> 4;
    const int rw = (wv >> 1) * 64, cw = (wv & 1) * 64;
#pragma unroll
    for (int mt = 0; mt < 4; mt++)
#pragma unroll
        for (int r = 0; r < 4; r++) {
            int m = m0 + rw + mt * 16 + quad * 4 + r;
#pragma unroll
            for (int nt = 0; nt < 4; nt++) {
                int n = n0 + cw + nt * 16 + l15;
                OUT[(size_t)m * D_MODEL + n] = acc[mt][nt][r] + bias[n];
            }
        }
}

extern "C" void kernel_launch(void* const* d_in, const int* in_sizes, int n_in,
                              void* d_out, int out_size, void* d_ws, size_t ws_size,
                              hipStream_t stream) {
    const float* x  = (const float*)d_in[0];
    // d_in[1] = mask (causal, hardcoded)
    const float* rc = (const float*)d_in[2];
    const float* rs = (const float*)d_in[3];
    const float* Wq = (const float*)d_in[4];
    const float* bq = (const float*)d_in[5];
    const float* Wk = (const float*)d_in[6];
    const float* bk = (const float*)d_in[7];
    const float* Wv = (const float*)d_in[8];
    const float* bv = (const float*)d_in[9];
    const float* Wo = (const float*)d_in[10];
    const float* bo = (const float*)d_in[11];

    char* ws = (char*)d_ws;
    __hip_bfloat16* xbf = (__hip_bfloat16*)(ws);                    // 16 MB
    __hip_bfloat16* wqb = (__hip_bfloat16*)(ws + (16u << 20));      // 2 MB
    __hip_bfloat16* wkb = (__hip_bfloat16*)(ws + (18u << 20));
    __hip_bfloat16* wvb = (__hip_bfloat16*)(ws + (20u << 20));
    __hip_bfloat16* wob = (__hip_bfloat16*)(ws + (22u << 20));
    __hip_bfloat16* Qb  = (__hip_bfloat16*)(ws + (24u << 20));      // 16 MB
    __hip_bfloat16* Kb  = (__hip_bfloat16*)(ws + (40u << 20));
    __hip_bfloat16* Vb  = (__hip_bfloat16*)(ws + (56u << 20));
    __hip_bfloat16* Cb  = (__hip_bfloat16*)(ws + (72u << 20));      // 16 MB
    float* out = (float*)d_out;

    f2bf4_kernel<<<8192, 256, 0, stream>>>((const float4*)x,  (__hip_bfloat162*)xbf, 2097152);
    f2bf4_kernel<<<1024, 256, 0, stream>>>((const float4*)Wq, (__hip_bfloat162*)wqb, 262144);
    f2bf4_kernel<<<1024, 256, 0, stream>>>((const float4*)Wk, (__hip_bfloat162*)wkb, 262144);
    f2bf4_kernel<<<1024, 256, 0, stream>>>((const float4*)Wv, (__hip_bfloat162*)wvb, 262144);
    f2bf4_kernel<<<1024, 256, 0, stream>>>((const float4*)Wo, (__hip_bfloat162*)wob, 262144);

    qkv_kernel<<<dim3(64, 8, 3), 256, 0, stream>>>(xbf, wqb, wkb, wvb, bq, bk, bv,
                                                   rc, rs, Qb, Kb, Vb);
    attn_kernel<<<dim3(32, 64), 256, 0, stream>>>(Qb, Kb, Vb, Cb);
    outproj_kernel<<<dim3(64, 8), 256, 0, stream>>>(Cb, wob, bo, out);
}

// Round 3
// 466.142 us; speedup vs baseline: 1.0825x; 1.0825x over previous
//
#include <hip/hip_runtime.h>
#include <hip/hip_bf16.h>

#define S_LEN 2048
#define D_MODEL 1024
#define NH 16
#define HDIM 64
#define B_SZ 4

typedef __attribute__((ext_vector_type(8))) short bf16x8;
typedef __attribute__((ext_vector_type(4))) float f32x4;

__device__ inline void gld16(const __hip_bfloat16* g, __hip_bfloat16* l) {
    __builtin_amdgcn_global_load_lds(
        (const __attribute__((address_space(1))) unsigned int*)g,
        (__attribute__((address_space(3))) unsigned int*)l, 16, 0, 0);
}

__device__ inline unsigned int pkbf(float a, float b) {
    float2 f; f.x = a; f.y = b;
    __hip_bfloat162 h = __float22bfloat162_rn(f);
    union { __hip_bfloat162 h; unsigned int u; } cv; cv.h = h; return cv.u;
}

// ---------------- fp32 -> bf16 convert (vectorized x4) ----------------
__global__ __launch_bounds__(256) void f2bf4_kernel(const float4* __restrict__ in,
                                                    __hip_bfloat162* __restrict__ out,
                                                    int n4) {
    int i = blockIdx.x * 256 + threadIdx.x;
    if (i < n4) {
        float4 v = in[i];
        __hip_bfloat162 a, b;
        a.x = __float2bfloat16(v.x); a.y = __float2bfloat16(v.y);
        b.x = __float2bfloat16(v.z); b.y = __float2bfloat16(v.w);
        out[2 * i]     = a;
        out[2 * i + 1] = b;
    }
}

// ---------------- shared GEMM mainloop: C[128x128] = X[128xK] * W[128xK]^T ----
__device__ inline void gemm_mainloop(const __hip_bfloat16* __restrict__ X,
                                     const __hip_bfloat16* __restrict__ W,
                                     __hip_bfloat16* As, __hip_bfloat16* Bs,
                                     int m0, int n0, f32x4 acc[4][4]) {
    const int tid = threadIdx.x;
    const int wv = tid >> 6, lane = tid & 63, l15 = lane & 15, quad = lane >> 4;
    const int rw = (wv >> 1) * 64, cw = (wv & 1) * 64;
    for (int k0 = 0; k0 < D_MODEL; k0 += 32) {
        __syncthreads();
#pragma unroll
        for (int i = 0; i < 2; i++) {
            int l = tid + 256 * i;
            int row = l >> 2, c8 = (l & 3) * 8;
            gld16(&X[(size_t)(m0 + row) * D_MODEL + k0 + c8], &As[row * 32 + c8]);
            gld16(&W[(size_t)(n0 + row) * D_MODEL + k0 + c8], &Bs[row * 32 + c8]);
        }
        __syncthreads();
        bf16x8 af[4], bfr[4];
#pragma unroll
        for (int t = 0; t < 4; t++)
            af[t] = *(const bf16x8*)&As[(rw + t * 16 + l15) * 32 + quad * 8];
#pragma unroll
        for (int t = 0; t < 4; t++)
            bfr[t] = *(const bf16x8*)&Bs[(cw + t * 16 + l15) * 32 + quad * 8];
#pragma unroll
        for (int mt = 0; mt < 4; mt++)
#pragma unroll
            for (int nt = 0; nt < 4; nt++)
                acc[mt][nt] = __builtin_amdgcn_mfma_f32_16x16x32_bf16(
                    af[mt], bfr[nt], acc[mt][nt], 0, 0, 0);
    }
}

// ---------------- QKV projection + RoPE + scatter to [B,H,S,hd] bf16 ---------
__global__ __launch_bounds__(256) void qkv_kernel(
    const __hip_bfloat16* __restrict__ X,
    const __hip_bfloat16* __restrict__ W0, const __hip_bfloat16* __restrict__ W1,
    const __hip_bfloat16* __restrict__ W2,
    const float* __restrict__ b0, const float* __restrict__ b1,
    const float* __restrict__ b2,
    const float* __restrict__ rc, const float* __restrict__ rs,
    __hip_bfloat16* __restrict__ Qo, __hip_bfloat16* __restrict__ Ko,
    __hip_bfloat16* __restrict__ Vo) {
    __shared__ __hip_bfloat16 As[128 * 32];
    __shared__ __hip_bfloat16 Bs[128 * 32];
    const int z = blockIdx.z;
    const __hip_bfloat16* W = (z == 0) ? W0 : ((z == 1) ? W1 : W2);
    const float* bias = (z == 0) ? b0 : ((z == 1) ? b1 : b2);
    f32x4 acc[4][4];
#pragma unroll
    for (int i = 0; i < 4; i++)
#pragma unroll
        for (int j = 0; j < 4; j++) acc[i][j] = (f32x4){0.f, 0.f, 0.f, 0.f};
    const int m0 = blockIdx.x * 128, n0 = blockIdx.y * 128;
    gemm_mainloop(X, W, As, Bs, m0, n0, acc);

    const int tid = threadIdx.x;
    const int wv = tid >> 6, lane = tid & 63, l15 = lane & 15, quad = lane >> 4;
    const int rw = (wv >> 1) * 64, cw = (wv & 1) * 64;

    if (z == 2) {
#pragma unroll
        for (int mt = 0; mt < 4; mt++)
#pragma unroll
            for (int r = 0; r < 4; r++) {
                int m = m0 + rw + mt * 16 + quad * 4 + r;
                int s = m & (S_LEN - 1), b = m >> 11;
#pragma unroll
                for (int nt = 0; nt < 4; nt++) {
                    int n = n0 + cw + nt * 16 + l15;
                    int h = n >> 6, hd = n & 63;
                    float v = acc[mt][nt][r] + bias[n];
                    Vo[(((size_t)(b * NH + h)) * S_LEN + s) * HDIM + hd] =
                        __float2bfloat16(v);
                }
            }
    } else {
        __hip_bfloat16* dst = (z == 0) ? Qo : Ko;
#pragma unroll
        for (int mt = 0; mt < 4; mt++)
#pragma unroll
            for (int r = 0; r < 4; r++) {
                int m = m0 + rw + mt * 16 + quad * 4 + r;
                int s = m & (S_LEN - 1), b = m >> 11;
#pragma unroll
                for (int nt = 0; nt < 2; nt++) {
                    int n1 = n0 + cw + nt * 16 + l15;
                    int h = n1 >> 6, hd1 = n1 & 63;  // hd1 in [0,32)
                    float y1 = acc[mt][nt][r] + bias[n1];
                    float y2 = acc[mt][nt + 2][r] + bias[n1 + 32];
                    float c1 = rc[s * HDIM + hd1], s1 = rs[s * HDIM + hd1];
                    float c2 = rc[s * HDIM + hd1 + 32], s2 = rs[s * HDIM + hd1 + 32];
                    size_t base = (((size_t)(b * NH + h)) * S_LEN + s) * HDIM;
                    dst[base + hd1]      = __float2bfloat16(y1 * c1 - y2 * s1);
                    dst[base + hd1 + 32] = __float2bfloat16(y2 * c2 + y1 * s2);
                }
            }
    }
}

// ---------------- flash attention, transposed-score formulation -------------
// Block: 4 waves x 32 queries = 128 q. Each wave: 2 q-tiles of 16.
// S^T = K·Q^T (C-layout: col=q, row=key) -> lane-scalar softmax state.
// ctx^T = V^T·P^T; P^T B-frags built via register shuffles (no LDS round-trip).
// K/V staged in double-buffered LDS, register-prefetched: 1 barrier/iter.
#define KP 72  // LDS pitch: 144B rows -> b128-aligned, even bank spread
__global__ __launch_bounds__(256) void attn_kernel(
    const __hip_bfloat16* __restrict__ Q, const __hip_bfloat16* __restrict__ K,
    const __hip_bfloat16* __restrict__ V, __hip_bfloat16* __restrict__ CTX) {
    __shared__ __hip_bfloat16 Kl[2][64 * KP];
    __shared__ __hip_bfloat16 Vt[2][64 * KP];   // transposed: [dim][key]
    const int tid = threadIdx.x;
    const int wv = tid >> 6, lane = tid & 63, l15 = lane & 15, quad = lane >> 4;
    const int bh = blockIdx.y;
    const int qb = (int)gridDim.x - 1 - (int)blockIdx.x;  // longest blocks first
    const int q0 = qb * 128;
    const int nkb = 2 * qb + 2;
    const size_t off = (size_t)bh * S_LEN * HDIM;
    const __hip_bfloat16* Qp = Q + off;
    const __hip_bfloat16* Kp = K + off;
    const __hip_bfloat16* Vp = V + off;

    // Q fragments (B-operand of S^T MFMA): Q[q=l15][d=quad*8+j]
    bf16x8 qf[2][2];
#pragma unroll
    for (int t = 0; t < 2; t++) {
        int qrow = q0 + wv * 32 + t * 16 + l15;
#pragma unroll
        for (int c = 0; c < 2; c++)
            qf[t][c] = *(const bf16x8*)&Qp[(size_t)qrow * HDIM + c * 32 + quad * 8];
    }

    float m_i[2] = {-1e30f, -1e30f}, l_i[2] = {0.f, 0.f};
    f32x4 acc[2][4];
#pragma unroll
    for (int t = 0; t < 2; t++)
#pragma unroll
        for (int nt = 0; nt < 4; nt++) acc[t][nt] = (f32x4){0.f, 0.f, 0.f, 0.f};

    const float SCL = 0.125f * 1.44269504088896340736f;  // 1/sqrt(64)*log2(e)

    // prefetch registers: K tile is 64 rows x 8 float4 (512 float4 = 2/thread)
    float4 kreg[2];
    unsigned short vreg[16];
    auto load_tile = [&](int kb) {
        const int k0 = kb * 64;
#pragma unroll
        for (int i = 0; i < 2; i++) {
            int l = tid + 256 * i;
            kreg[i] = *(const float4*)&Kp[(size_t)(k0 + (l >> 3)) * HDIM + (l & 7) * 8];
        }
#pragma unroll
        for (int j = 0; j < 16; j++)
            vreg[j] = *(const unsigned short*)&Vp[(size_t)(k0 + wv * 16 + j) * HDIM + lane];
    };
    auto store_tile = [&](int buf) {
#pragma unroll
        for (int i = 0; i < 2; i++) {
            int l = tid + 256 * i;
            *(float4*)&Kl[buf][(l >> 3) * KP + (l & 7) * 8] = kreg[i];
        }
        union { bf16x8 v; unsigned short u[8]; } p0, p1;
#pragma unroll
        for (int j = 0; j < 8; j++) { p0.u[j] = vreg[j]; p1.u[j] = vreg[8 + j]; }
        *(bf16x8*)&Vt[buf][lane * KP + wv * 16]     = p0.v;
        *(bf16x8*)&Vt[buf][lane * KP + wv * 16 + 8] = p1.v;
    };

    load_tile(0);
    for (int kb = 0; kb < nkb; kb++) {
        const int buf = kb & 1, k0 = kb * 64;
        store_tile(buf);
        __syncthreads();
        if (kb + 1 < nkb) load_tile(kb + 1);  // overlaps with compute below

        unsigned int pk[2][8] = {{0,0,0,0,0,0,0,0},{0,0,0,0,0,0,0,0}};
#pragma unroll
        for (int t = 0; t < 2; t++) {
            const int qbt = q0 + wv * 32 + t * 16;
            if (k0 > qbt + 15) continue;  // whole tile masked (wave-uniform)
            f32x4 sa[4];
#pragma unroll
            for (int st = 0; st < 4; st++) sa[st] = (f32x4){0.f, 0.f, 0.f, 0.f};
#pragma unroll
            for (int c = 0; c < 2; c++)
#pragma unroll
                for (int st = 0; st < 4; st++) {
                    bf16x8 kf = *(const bf16x8*)&Kl[buf][(st * 16 + l15) * KP + c * 32 + quad * 8];
                    sa[st] = __builtin_amdgcn_mfma_f32_16x16x32_bf16(kf, qf[t][c], sa[st], 0, 0, 0);
                }
            const bool needMask = (k0 + 63 > qbt);
            const int q = qbt + l15;
            float sv[16];
#pragma unroll
            for (int st = 0; st < 4; st++)
#pragma unroll
                for (int r = 0; r < 4; r++) {
                    float s = sa[st][r] * SCL;
                    if (needMask && (k0 + st * 16 + quad * 4 + r > q)) s = -1e30f;
                    sv[st * 4 + r] = s;
                }
            float mx = sv[0];
#pragma unroll
            for (int i = 1; i < 16; i++) mx = fmaxf(mx, sv[i]);
            mx = fmaxf(mx, __shfl_xor(mx, 16));
            mx = fmaxf(mx, __shfl_xor(mx, 32));
            float mn = fmaxf(m_i[t], mx);
            float al = __builtin_exp2f(m_i[t] - mn);
            m_i[t] = mn;
            float p[16], ls = 0.f;
#pragma unroll
            for (int i = 0; i < 16; i++) { p[i] = __builtin_exp2f(sv[i] - mn); ls += p[i]; }
            ls += __shfl_xor(ls, 16);
            ls += __shfl_xor(ls, 32);
            l_i[t] = l_i[t] * al + ls;
#pragma unroll
            for (int nt = 0; nt < 4; nt++) acc[t][nt] *= al;
#pragma unroll
            for (int st = 0; st < 4; st++) {
                pk[t][st * 2 + 0] = pkbf(p[st * 4 + 0], p[st * 4 + 1]);
                pk[t][st * 2 + 1] = pkbf(p[st * 4 + 2], p[st * 4 + 3]);
            }
        }
        // PV: ctx^T += V^T · P^T
        const int srcA = l15 + ((quad & 1) << 5);
        const int srcB = srcA + 16;
        const bool hi = (quad >> 1) != 0;
#pragma unroll
        for (int c = 0; c < 2; c++) {
            bf16x8 vf[4];
#pragma unroll
            for (int nt = 0; nt < 4; nt++)
                vf[nt] = *(const bf16x8*)&Vt[buf][(nt * 16 + l15) * KP + c * 32 + quad * 8];
#pragma unroll
            for (int t = 0; t < 2; t++) {
                unsigned int a0 = __shfl((int)pk[t][4 * c + 0], srcA);
                unsigned int a1 = __shfl((int)pk[t][4 * c + 1], srcA);
                unsigned int a2 = __shfl((int)pk[t][4 * c + 0], srcB);
                unsigned int a3 = __shfl((int)pk[t][4 * c + 1], srcB);
                unsigned int b0 = __shfl((int)pk[t][4 * c + 2], srcA);
                unsigned int b1 = __shfl((int)pk[t][4 * c + 3], srcA);
                unsigned int b2 = __shfl((int)pk[t][4 * c + 2], srcB);
                unsigned int b3 = __shfl((int)pk[t][4 * c + 3], srcB);
                union { unsigned int u[4]; bf16x8 v; } pf;
                pf.u[0] = hi ? b0 : a0;
                pf.u[1] = hi ? b1 : a1;
                pf.u[2] = hi ? b2 : a2;
                pf.u[3] = hi ? b3 : a3;
#pragma unroll
                for (int nt = 0; nt < 4; nt++)
                    acc[t][nt] = __builtin_amdgcn_mfma_f32_16x16x32_bf16(vf[nt], pf.v, acc[t][nt], 0, 0, 0);
            }
        }
    }

    const int b = bh >> 4, h = bh & 15;
#pragma unroll
    for (int t = 0; t < 2; t++) {
        const int q = q0 + wv * 32 + t * 16 + l15;
        const float inv = 1.0f / l_i[t];
#pragma unroll
        for (int nt = 0; nt < 4; nt++) {
            uint2 st2;
            st2.x = pkbf(acc[t][nt][0] * inv, acc[t][nt][1] * inv);
            st2.y = pkbf(acc[t][nt][2] * inv, acc[t][nt][3] * inv);
            *(uint2*)&CTX[((size_t)(b * S_LEN + q)) * D_MODEL + h * HDIM + nt * 16 + quad * 4] = st2;
        }
    }
}

// ---------------- output projection: fp32 out = ctx @ Wo^T + bo --------------
__global__ __launch_bounds__(256) void outproj_kernel(
    const __hip_bfloat16* __restrict__ X, const __hip_bfloat16* __restrict__ W,
    const float* __restrict__ bias, float* __restrict__ OUT) {
    __shared__ __hip_bfloat16 As[128 * 32];
    __shared__ __hip_bfloat16 Bs[128 * 32];
    f32x4 acc[4][4];
#pragma unroll
    for (int i = 0; i < 4; i++)
#pragma unroll
        for (int j = 0; j < 4; j++) acc[i][j] = (f32x4){0.f, 0.f, 0.f, 0.f};
    const int m0 = blockIdx.x * 128, n0 = blockIdx.y * 128;
    gemm_mainloop(X, W, As, Bs, m0, n0, acc);
    const int tid = threadIdx.x;
    const int wv = tid >> 6, lane = tid & 63, l15 = lane & 15, quad = lane >> 4;
    const int rw = (wv >> 1) * 64, cw = (wv & 1) * 64;
#pragma unroll
    for (int mt = 0; mt < 4; mt++)
#pragma unroll
        for (int r = 0; r < 4; r++) {
            int m = m0 + rw + mt * 16 + quad * 4 + r;
#pragma unroll
            for (int nt = 0; nt < 4; nt++) {
                int n = n0 + cw + nt * 16 + l15;
                OUT[(size_t)m * D_MODEL + n] = acc[mt][nt][r] + bias[n];
            }
        }
}

extern "C" void kernel_launch(void* const* d_in, const int* in_sizes, int n_in,
                              void* d_out, int out_size, void* d_ws, size_t ws_size,
                              hipStream_t stream) {
    const float* x  = (const float*)d_in[0];
    const float* rc = (const float*)d_in[2];
    const float* rs = (const float*)d_in[3];
    const float* Wq = (const float*)d_in[4];
    const float* bq = (const float*)d_in[5];
    const float* Wk = (const float*)d_in[6];
    const float* bk = (const float*)d_in[7];
    const float* Wv = (const float*)d_in[8];
    const float* bv = (const float*)d_in[9];
    const float* Wo = (const float*)d_in[10];
    const float* bo = (const float*)d_in[11];

    char* ws = (char*)d_ws;
    __hip_bfloat16* xbf = (__hip_bfloat16*)(ws);                    // 16 MB
    __hip_bfloat16* wqb = (__hip_bfloat16*)(ws + (16u << 20));      // 2 MB
    __hip_bfloat16* wkb = (__hip_bfloat16*)(ws + (18u << 20));
    __hip_bfloat16* wvb = (__hip_bfloat16*)(ws + (20u << 20));
    __hip_bfloat16* wob = (__hip_bfloat16*)(ws + (22u << 20));
    __hip_bfloat16* Qb  = (__hip_bfloat16*)(ws + (24u << 20));      // 16 MB
    __hip_bfloat16* Kb  = (__hip_bfloat16*)(ws + (40u << 20));
    __hip_bfloat16* Vb  = (__hip_bfloat16*)(ws + (56u << 20));
    __hip_bfloat16* Cb  = (__hip_bfloat16*)(ws + (72u << 20));      // 16 MB
    float* out = (float*)d_out;

    f2bf4_kernel<<<8192, 256, 0, stream>>>((const float4*)x,  (__hip_bfloat162*)xbf, 2097152);
    f2bf4_kernel<<<1024, 256, 0, stream>>>((const float4*)Wq, (__hip_bfloat162*)wqb, 262144);
    f2bf4_kernel<<<1024, 256, 0, stream>>>((const float4*)Wk, (__hip_bfloat162*)wkb, 262144);
    f2bf4_kernel<<<1024, 256, 0, stream>>>((const float4*)Wv, (__hip_bfloat162*)wvb, 262144);
    f2bf4_kernel<<<1024, 256, 0, stream>>>((const float4*)Wo, (__hip_bfloat162*)wob, 262144);

    qkv_kernel<<<dim3(64, 8, 3), 256, 0, stream>>>(xbf, wqb, wkb, wvb, bq, bk, bv,
                                                   rc, rs, Qb, Kb, Vb);
    attn_kernel<<<dim3(16, 64), 256, 0, stream>>>(Qb, Kb, Vb, Cb);
    outproj_kernel<<<dim3(64, 8), 256, 0, stream>>>(Cb, wob, bo, out);
}